// Round 2
// baseline (384.879 us; speedup 1.0000x reference)
//
#include <hip/hip_runtime.h>

#define T_DIM 1024
#define B_DIM 64
#define H_DIM 1024
#define OSPLIT 16      // o-reduction split for v = hidden@W (512 blocks, depth 64)

// ---------------------------------------------------------------------------
// Kernel 1: v_part[os][b][h] = sum_{o in chunk} hidden[b][o] * W[o][h]
// grid (H/64, B/32, OSPLIT) = (16,2,16) = 512 blocks, 256 threads (4 waves).
// Wave w handles b in [y*32 + 8w, +8): 8 fp32 accs/thread, thread owns one h.
// hidden chunk in LDS (same-address broadcast reads -> conflict-free).
// W row reads coalesced (64 lanes x 4B); serial depth 64 strided loads.
// ---------------------------------------------------------------------------
__global__ __launch_bounds__(256) void gemv_hw(const float* __restrict__ hidden,
                                               const float* __restrict__ W,
                                               float* __restrict__ v_part) {
    __shared__ float hid_s[32 * 64];               // 8 KB: [bi][o]
    const int tid  = threadIdx.x;                  // 0..255
    const int lane = tid & 63;
    const int wv   = tid >> 6;                     // 0..3
    const int h    = blockIdx.x * 64 + lane;
    const int b0   = blockIdx.y * 32;
    const int o0   = blockIdx.z * 64;

    // stage hidden[b0..b0+31][o0..o0+63]: 512 float4s, 2 per thread
#pragma unroll
    for (int r = 0; r < 2; ++r) {
        const int i  = tid + 256 * r;
        const int bi = i >> 4;                     // 16 float4 per b-row
        const int o4 = i & 15;
        reinterpret_cast<float4*>(hid_s)[i] =
            reinterpret_cast<const float4*>(hidden + (size_t)(b0 + bi) * H_DIM + o0)[o4];
    }
    __syncthreads();

    float acc[8];
#pragma unroll
    for (int j = 0; j < 8; ++j) acc[j] = 0.f;

    const float* wcol = W + (size_t)o0 * H_DIM + h;
    const float* hrow = hid_s + (wv * 8) * 64;     // this wave's 8 b-rows
#pragma unroll 4
    for (int o = 0; o < 64; ++o) {
        const float w = wcol[(size_t)o * H_DIM];
#pragma unroll
        for (int j = 0; j < 8; ++j) acc[j] += hrow[j * 64 + o] * w;
    }

    float* vp = v_part + ((size_t)blockIdx.z * B_DIM + b0 + wv * 8) * H_DIM + h;
#pragma unroll
    for (int j = 0; j < 8; ++j) vp[(size_t)j * H_DIM] = acc[j];
}

// ---------------------------------------------------------------------------
// Kernel 1b: v[b][h] = sum_os v_part[os][b][h]. 4 MB read (L2), 256 KB write.
// grid 64 x 256 threads, one float4 per thread.
// ---------------------------------------------------------------------------
__global__ __launch_bounds__(256) void reduce_v(const float* __restrict__ v_part,
                                                float* __restrict__ v) {
    const int i = blockIdx.x * 256 + threadIdx.x;  // float4 index into [B*H/4)
    float4 s = make_float4(0.f, 0.f, 0.f, 0.f);
#pragma unroll
    for (int os = 0; os < OSPLIT; ++os) {
        const float4 p = reinterpret_cast<const float4*>(
            v_part + (size_t)os * B_DIM * H_DIM)[i];
        s.x += p.x; s.y += p.y; s.z += p.z; s.w += p.w;
    }
    reinterpret_cast<float4*>(v)[i] = s;
}

// ---------------------------------------------------------------------------
// Kernel 2 (dominant, HBM-bound): energies[b][t] = enc[t][b][:] . v[b][:]
// grid (T/16, B) = (64,64) = 4096 blocks, 256 threads (4 waves).
// Block stages v[b] (4 KB) once, amortized over 16 t-rows.
// Wave w handles t = x*16 + 4w + j, j<4: 16 independent float4 loads per
// lane in flight; shuffle-reduce per row.
// ROUND-1 CHANGE: plain float4 loads (was __builtin_nontemporal_load) —
// the 6.3 TB/s measured ceiling recipe uses plain loads; nt is unmeasured
// on gfx950 and enc has no reuse to protect anyway.
// ---------------------------------------------------------------------------
__global__ __launch_bounds__(256) void energies_k(const float* __restrict__ enc,
                                                  const float* __restrict__ v,
                                                  float* __restrict__ energies) {
    __shared__ float v_s[H_DIM];                   // 4 KB
    const int tid  = threadIdx.x;
    const int lane = tid & 63;
    const int wv   = tid >> 6;
    const int b    = blockIdx.y;
    const int t0   = blockIdx.x * 16 + wv * 4;

    reinterpret_cast<float4*>(v_s)[tid] =
        reinterpret_cast<const float4*>(v + (size_t)b * H_DIM)[tid];
    __syncthreads();

    const float4* vrow = reinterpret_cast<const float4*>(v_s);
    float4 vk[4];
#pragma unroll
    for (int k = 0; k < 4; ++k) vk[k] = vrow[k * 64 + lane];

    float p[4];
#pragma unroll
    for (int j = 0; j < 4; ++j) {
        const float* erow = enc + ((size_t)(t0 + j) * B_DIM + b) * H_DIM;
        float acc = 0.f;
#pragma unroll
        for (int k = 0; k < 4; ++k) {
            const float4 e = *reinterpret_cast<const float4*>(erow + (k * 64 + lane) * 4);
            acc += e.x * vk[k].x + e.y * vk[k].y + e.z * vk[k].z + e.w * vk[k].w;
        }
        p[j] = acc;
    }
#pragma unroll
    for (int j = 0; j < 4; ++j) {
#pragma unroll
        for (int off = 32; off >= 1; off >>= 1) p[j] += __shfl_down(p[j], off, 64);
        if (lane == 0) energies[(size_t)b * T_DIM + t0 + j] = p[j];
    }
}

// ---------------------------------------------------------------------------
// Kernel 3: softmax over t per b. Bias dropped (constant over t -> cancels).
// ---------------------------------------------------------------------------
__global__ __launch_bounds__(256) void softmax_k(const float* __restrict__ energies,
                                                 float* __restrict__ out) {
    __shared__ float red[4];
    const int b    = blockIdx.x;
    const int tid  = threadIdx.x;
    const int lane = tid & 63;
    const int wave = tid >> 6;

    float4 e = reinterpret_cast<const float4*>(energies + (size_t)b * T_DIM)[tid];

    float m = fmaxf(fmaxf(e.x, e.y), fmaxf(e.z, e.w));
#pragma unroll
    for (int off = 32; off >= 1; off >>= 1) m = fmaxf(m, __shfl_xor(m, off, 64));
    if (lane == 0) red[wave] = m;
    __syncthreads();
    m = fmaxf(fmaxf(red[0], red[1]), fmaxf(red[2], red[3]));

    e.x = __expf(e.x - m); e.y = __expf(e.y - m);
    e.z = __expf(e.z - m); e.w = __expf(e.w - m);
    float s = e.x + e.y + e.z + e.w;
#pragma unroll
    for (int off = 32; off >= 1; off >>= 1) s += __shfl_xor(s, off, 64);
    __syncthreads();
    if (lane == 0) red[wave] = s;
    __syncthreads();
    s = red[0] + red[1] + red[2] + red[3];

    const float inv = 1.0f / s;
    const float4 o4 = make_float4(e.x * inv, e.y * inv, e.z * inv, e.w * inv);
    reinterpret_cast<float4*>(out + (size_t)b * T_DIM)[tid] = o4;
}

// ---------------------------------------------------------------------------
extern "C" void kernel_launch(void* const* d_in, const int* in_sizes, int n_in,
                              void* d_out, int out_size, void* d_ws, size_t ws_size,
                              hipStream_t stream) {
    (void)in_sizes; (void)n_in; (void)out_size; (void)ws_size;
    const float* hidden = (const float*)d_in[0];   // [1,B,H]
    const float* enc    = (const float*)d_in[1];   // [T,B,H]
    const float* W      = (const float*)d_in[2];   // [H,H]
    // d_in[3] = bias: constant over t -> cancelled by softmax, unused.

    float* v_part   = (float*)d_ws;                                       // 4 MB
    float* v        = v_part + (size_t)OSPLIT * B_DIM * H_DIM;            // 256 KB
    float* energies = v + (size_t)B_DIM * H_DIM;                          // 256 KB
    float* out = (float*)d_out;

    gemv_hw   <<<dim3(H_DIM / 64, B_DIM / 32, OSPLIT), 256, 0, stream>>>(hidden, W, v_part);
    reduce_v  <<<dim3(B_DIM * H_DIM / 4 / 256),        256, 0, stream>>>(v_part, v);
    energies_k<<<dim3(T_DIM / 16, B_DIM),              256, 0, stream>>>(enc, v, energies);
    softmax_k <<<dim3(B_DIM),                          256, 0, stream>>>(energies, out);
}

// Round 3
// 354.986 us; speedup vs baseline: 1.0842x; 1.0842x over previous
//
#include <hip/hip_runtime.h>

#define T_DIM 1024
#define B_DIM 64
#define H_DIM 1024
#define OSPLIT 16      // o-reduction split for v = hidden@W (512 blocks, depth 64)

// native clang vector type -> __builtin_nontemporal_load accepts it
typedef float floatx4 __attribute__((ext_vector_type(4)));

// nontemporal float4 load (enc is a read-once 268 MB stream).
// Round-2 A/B: plain loads measured 384.9 us vs 354.8 us with nt (prior
// session) -> restore nt; mechanism: no L2 allocation for zero-reuse stream.
__device__ __forceinline__ float4 ldnt4(const float* p) {
    floatx4 r = __builtin_nontemporal_load(reinterpret_cast<const floatx4*>(p));
    return make_float4(r.x, r.y, r.z, r.w);
}

// ---------------------------------------------------------------------------
// Kernel 1: v_part[os][b][h] = sum_{o in chunk} hidden[b][o] * W[o][h]
// grid (H/64, B/32, OSPLIT) = (16,2,16) = 512 blocks, 256 threads (4 waves).
// Wave w handles b in [y*32 + 8w, +8): 8 fp32 accs/thread, thread owns one h.
// hidden chunk in LDS (same-address broadcast reads -> conflict-free).
// W row reads coalesced (64 lanes x 4B); serial depth 64 strided loads.
// ---------------------------------------------------------------------------
__global__ __launch_bounds__(256) void gemv_hw(const float* __restrict__ hidden,
                                               const float* __restrict__ W,
                                               float* __restrict__ v_part) {
    __shared__ float hid_s[32 * 64];               // 8 KB: [bi][o]
    const int tid  = threadIdx.x;                  // 0..255
    const int lane = tid & 63;
    const int wv   = tid >> 6;                     // 0..3
    const int h    = blockIdx.x * 64 + lane;
    const int b0   = blockIdx.y * 32;
    const int o0   = blockIdx.z * 64;

    // stage hidden[b0..b0+31][o0..o0+63]: 512 float4s, 2 per thread
#pragma unroll
    for (int r = 0; r < 2; ++r) {
        const int i  = tid + 256 * r;
        const int bi = i >> 4;                     // 16 float4 per b-row
        const int o4 = i & 15;
        reinterpret_cast<float4*>(hid_s)[i] =
            reinterpret_cast<const float4*>(hidden + (size_t)(b0 + bi) * H_DIM + o0)[o4];
    }
    __syncthreads();

    float acc[8];
#pragma unroll
    for (int j = 0; j < 8; ++j) acc[j] = 0.f;

    const float* wcol = W + (size_t)o0 * H_DIM + h;
    const float* hrow = hid_s + (wv * 8) * 64;     // this wave's 8 b-rows
#pragma unroll 4
    for (int o = 0; o < 64; ++o) {
        const float w = wcol[(size_t)o * H_DIM];
#pragma unroll
        for (int j = 0; j < 8; ++j) acc[j] += hrow[j * 64 + o] * w;
    }

    float* vp = v_part + ((size_t)blockIdx.z * B_DIM + b0 + wv * 8) * H_DIM + h;
#pragma unroll
    for (int j = 0; j < 8; ++j) vp[(size_t)j * H_DIM] = acc[j];
}

// ---------------------------------------------------------------------------
// Kernel 1b: v[b][h] = sum_os v_part[os][b][h]. 4 MB read (L2), 256 KB write.
// grid 64 x 256 threads, one float4 per thread.
// ---------------------------------------------------------------------------
__global__ __launch_bounds__(256) void reduce_v(const float* __restrict__ v_part,
                                                float* __restrict__ v) {
    const int i = blockIdx.x * 256 + threadIdx.x;  // float4 index into [B*H/4)
    float4 s = make_float4(0.f, 0.f, 0.f, 0.f);
#pragma unroll
    for (int os = 0; os < OSPLIT; ++os) {
        const float4 p = reinterpret_cast<const float4*>(
            v_part + (size_t)os * B_DIM * H_DIM)[i];
        s.x += p.x; s.y += p.y; s.z += p.z; s.w += p.w;
    }
    reinterpret_cast<float4*>(v)[i] = s;
}

// ---------------------------------------------------------------------------
// Kernel 2 (dominant, HBM-bound): energies[b][t] = enc[t][b][:] . v[b][:]
// grid (T/16, B) = (64,64) = 4096 blocks, 256 threads (4 waves).
// Block stages v[b] (4 KB) once, amortized over 16 t-rows.
// Wave w handles t = x*16 + 4w + j, j<4: 16 independent nontemporal float4
// loads per lane in flight; shuffle-reduce per row.
// ---------------------------------------------------------------------------
__global__ __launch_bounds__(256) void energies_k(const float* __restrict__ enc,
                                                  const float* __restrict__ v,
                                                  float* __restrict__ energies) {
    __shared__ float v_s[H_DIM];                   // 4 KB
    const int tid  = threadIdx.x;
    const int lane = tid & 63;
    const int wv   = tid >> 6;
    const int b    = blockIdx.y;
    const int t0   = blockIdx.x * 16 + wv * 4;

    reinterpret_cast<float4*>(v_s)[tid] =
        reinterpret_cast<const float4*>(v + (size_t)b * H_DIM)[tid];
    __syncthreads();

    const float4* vrow = reinterpret_cast<const float4*>(v_s);
    float4 vk[4];
#pragma unroll
    for (int k = 0; k < 4; ++k) vk[k] = vrow[k * 64 + lane];

    float p[4];
#pragma unroll
    for (int j = 0; j < 4; ++j) {
        const float* erow = enc + ((size_t)(t0 + j) * B_DIM + b) * H_DIM;
        float acc = 0.f;
#pragma unroll
        for (int k = 0; k < 4; ++k) {
            const float4 e = ldnt4(erow + (k * 64 + lane) * 4);
            acc += e.x * vk[k].x + e.y * vk[k].y + e.z * vk[k].z + e.w * vk[k].w;
        }
        p[j] = acc;
    }
#pragma unroll
    for (int j = 0; j < 4; ++j) {
#pragma unroll
        for (int off = 32; off >= 1; off >>= 1) p[j] += __shfl_down(p[j], off, 64);
        if (lane == 0) energies[(size_t)b * T_DIM + t0 + j] = p[j];
    }
}

// ---------------------------------------------------------------------------
// Kernel 3: softmax over t per b. Bias dropped (constant over t -> cancels).
// ---------------------------------------------------------------------------
__global__ __launch_bounds__(256) void softmax_k(const float* __restrict__ energies,
                                                 float* __restrict__ out) {
    __shared__ float red[4];
    const int b    = blockIdx.x;
    const int tid  = threadIdx.x;
    const int lane = tid & 63;
    const int wave = tid >> 6;

    float4 e = reinterpret_cast<const float4*>(energies + (size_t)b * T_DIM)[tid];

    float m = fmaxf(fmaxf(e.x, e.y), fmaxf(e.z, e.w));
#pragma unroll
    for (int off = 32; off >= 1; off >>= 1) m = fmaxf(m, __shfl_xor(m, off, 64));
    if (lane == 0) red[wave] = m;
    __syncthreads();
    m = fmaxf(fmaxf(red[0], red[1]), fmaxf(red[2], red[3]));

    e.x = __expf(e.x - m); e.y = __expf(e.y - m);
    e.z = __expf(e.z - m); e.w = __expf(e.w - m);
    float s = e.x + e.y + e.z + e.w;
#pragma unroll
    for (int off = 32; off >= 1; off >>= 1) s += __shfl_xor(s, off, 64);
    __syncthreads();
    if (lane == 0) red[wave] = s;
    __syncthreads();
    s = red[0] + red[1] + red[2] + red[3];

    const float inv = 1.0f / s;
    const float4 o4 = make_float4(e.x * inv, e.y * inv, e.z * inv, e.w * inv);
    reinterpret_cast<float4*>(out + (size_t)b * T_DIM)[tid] = o4;
}

// ---------------------------------------------------------------------------
extern "C" void kernel_launch(void* const* d_in, const int* in_sizes, int n_in,
                              void* d_out, int out_size, void* d_ws, size_t ws_size,
                              hipStream_t stream) {
    (void)in_sizes; (void)n_in; (void)out_size; (void)ws_size;
    const float* hidden = (const float*)d_in[0];   // [1,B,H]
    const float* enc    = (const float*)d_in[1];   // [T,B,H]
    const float* W      = (const float*)d_in[2];   // [H,H]
    // d_in[3] = bias: constant over t -> cancelled by softmax, unused.

    float* v_part   = (float*)d_ws;                                       // 4 MB
    float* v        = v_part + (size_t)OSPLIT * B_DIM * H_DIM;            // 256 KB
    float* energies = v + (size_t)B_DIM * H_DIM;                          // 256 KB
    float* out = (float*)d_out;

    gemv_hw   <<<dim3(H_DIM / 64, B_DIM / 32, OSPLIT), 256, 0, stream>>>(hidden, W, v_part);
    reduce_v  <<<dim3(B_DIM * H_DIM / 4 / 256),        256, 0, stream>>>(v_part, v);
    energies_k<<<dim3(T_DIM / 16, B_DIM),              256, 0, stream>>>(enc, v, energies);
    softmax_k <<<dim3(B_DIM),                          256, 0, stream>>>(energies, out);
}